// Round 1
// baseline (129.826 us; speedup 1.0000x reference)
//
#include <hip/hip_runtime.h>
#include <hip/hip_bf16.h>

// 3D shifted-window attention, fully fused: per-block = one output window.
// Output window (p,q,r): QK from window (q,r,p), V from (p,q,r),
// x_mask iff q==15, y_mask iff r==15 (z_mask never applied - faithful to ref).
// Roll(-2) folded into loads, roll(+2) folded into stores.

using bf8   = __attribute__((ext_vector_type(8))) short;   // 8 x bf16 (4 VGPR)
using f32x4 = __attribute__((ext_vector_type(4))) float;

__device__ __forceinline__ short f2b(float f) {
  __hip_bfloat16 h = __float2bfloat16(f);
  return *reinterpret_cast<short*>(&h);
}
__device__ __forceinline__ unsigned pk2(float a, float b) {
  return (unsigned)(unsigned short)f2b(a) | ((unsigned)(unsigned short)f2b(b) << 16);
}

__global__ void prep_weights(const float* __restrict__ wq, const float* __restrict__ wo,
                             short* __restrict__ wqb, short* __restrict__ wob) {
  int i = blockIdx.x * 256 + threadIdx.x;
  if (i < 288 * 96) wqb[i] = f2b(wq[i]);
  if (i < 96 * 96)  wob[i] = f2b(wo[i]);
}

// Load one 4x4x4 window of x (rolled by -2 on each axis) into LDS as bf16 [64][96].
__device__ __forceinline__ void load_window_bf16(short* __restrict__ ys,
    const float* __restrict__ x, int wx, int wy, int wz, int tid) {
  #pragma unroll
  for (int it = 0; it < 6; ++it) {
    int idx = tid + it * 256;            // 0..1535 float4s
    int s   = idx / 24;
    int c4  = (idx - s * 24) * 4;
    int sx = s >> 4, sy = (s >> 2) & 3, sz = s & 3;
    int gx = (wx * 4 + sx + 2) & 63;
    int gy = (wy * 4 + sy + 2) & 63;
    int gz = (wz * 4 + sz + 2) & 63;
    const float4 v = *reinterpret_cast<const float4*>(
        &x[(size_t)((gx * 64 + gy) * 64 + gz) * 96 + c4]);
    unsigned* dst = reinterpret_cast<unsigned*>(&ys[s * 96 + c4]);
    dst[0] = pk2(v.x, v.y);
    dst[1] = pk2(v.z, v.w);
  }
}

__global__ __launch_bounds__(256, 2)
void fused_swin3d(const float* __restrict__ x,
                  const short* __restrict__ wqb,   // [288][96] bf16
                  const short* __restrict__ wob,   // [96][96]  bf16
                  const float* __restrict__ bo,    // [96] fp32
                  float* __restrict__ out) {
  __shared__ short ls_q [64 * 96];   // Q bf16 [s][ch]   (later reused as O)
  __shared__ short ls_k [64 * 96];   // K bf16 [s][ch]
  __shared__ short ls_vt[96 * 72];   // V bf16 transposed [ch][s], stride 72
  __shared__ short ls_p [64 * 72];   // P bf16 [i][j], stride 72
  __shared__ float ls_s [64 * 67];   // S fp32 [i][j], stride 67 (also holds ys)

  short* ys = reinterpret_cast<short*>(ls_s);
  short* lo = ls_q;

  const int w  = blockIdx.x;
  const int p  = w >> 8, q = (w >> 4) & 15, r = w & 15;
  const int tid  = threadIdx.x;
  const int lane = tid & 63;
  const int wv   = tid >> 6;         // wave id = M-tile (rows wv*16..wv*16+15)
  const int lr   = lane & 15;
  const int kg   = lane >> 4;
  const int arow  = wv * 16 + lr;    // A/B-frag row
  const int drow0 = wv * 16 + kg * 4;// D-frag first row

  // ---- Phase 1: ys = x(window (q,r,p)); compute Q (scaled) and K -------------
  load_window_bf16(ys, x, q, r, p, tid);
  __syncthreads();
  bf8 af0 = *reinterpret_cast<const bf8*>(&ys[arow * 96 +  0 + kg * 8]);
  bf8 af1 = *reinterpret_cast<const bf8*>(&ys[arow * 96 + 32 + kg * 8]);
  bf8 af2 = *reinterpret_cast<const bf8*>(&ys[arow * 96 + 64 + kg * 8]);
  const float QS = 0.17677669529663687f;   // 1/sqrt(32)
  #pragma unroll
  for (int n = 0; n < 12; ++n) {
    f32x4 acc = {0.f, 0.f, 0.f, 0.f};
    const short* wrow = &wqb[(n * 16 + lr) * 96 + kg * 8];
    acc = __builtin_amdgcn_mfma_f32_16x16x32_bf16(af0, *reinterpret_cast<const bf8*>(wrow +  0), acc, 0, 0, 0);
    acc = __builtin_amdgcn_mfma_f32_16x16x32_bf16(af1, *reinterpret_cast<const bf8*>(wrow + 32), acc, 0, 0, 0);
    acc = __builtin_amdgcn_mfma_f32_16x16x32_bf16(af2, *reinterpret_cast<const bf8*>(wrow + 64), acc, 0, 0, 0);
    if (n < 6) {
      #pragma unroll
      for (int ri = 0; ri < 4; ++ri)
        ls_q[(drow0 + ri) * 96 + n * 16 + lr] = f2b(acc[ri] * QS);
    } else {
      #pragma unroll
      for (int ri = 0; ri < 4; ++ri)
        ls_k[(drow0 + ri) * 96 + (n - 6) * 16 + lr] = f2b(acc[ri]);
    }
  }
  __syncthreads();

  // ---- Phase 2: ys = x(window (p,q,r)); compute V, store transposed ----------
  load_window_bf16(ys, x, p, q, r, tid);
  __syncthreads();
  af0 = *reinterpret_cast<const bf8*>(&ys[arow * 96 +  0 + kg * 8]);
  af1 = *reinterpret_cast<const bf8*>(&ys[arow * 96 + 32 + kg * 8]);
  af2 = *reinterpret_cast<const bf8*>(&ys[arow * 96 + 64 + kg * 8]);
  #pragma unroll
  for (int n = 0; n < 6; ++n) {
    f32x4 acc = {0.f, 0.f, 0.f, 0.f};
    const short* wrow = &wqb[(192 + n * 16 + lr) * 96 + kg * 8];
    acc = __builtin_amdgcn_mfma_f32_16x16x32_bf16(af0, *reinterpret_cast<const bf8*>(wrow +  0), acc, 0, 0, 0);
    acc = __builtin_amdgcn_mfma_f32_16x16x32_bf16(af1, *reinterpret_cast<const bf8*>(wrow + 32), acc, 0, 0, 0);
    acc = __builtin_amdgcn_mfma_f32_16x16x32_bf16(af2, *reinterpret_cast<const bf8*>(wrow + 64), acc, 0, 0, 0);
    #pragma unroll
    for (int ri = 0; ri < 4; ++ri)
      ls_vt[(n * 16 + lr) * 72 + drow0 + ri] = f2b(acc[ri]);   // Vt[ch][s]
  }
  __syncthreads();

  // ---- Phase 3: per-head S = QK^T (+mask), softmax, O += P V -----------------
  const bool mx = (q == 15), my = (r == 15);
  f32x4 acc_o[3][2];
  #pragma unroll
  for (int h = 0; h < 3; ++h)
    #pragma unroll
    for (int n = 0; n < 2; ++n)
      acc_o[h][n] = (f32x4){0.f, 0.f, 0.f, 0.f};

  #pragma unroll
  for (int h = 0; h < 3; ++h) {
    bf8 qa = *reinterpret_cast<const bf8*>(&ls_q[arow * 96 + h * 32 + kg * 8]);
    #pragma unroll
    for (int n = 0; n < 4; ++n) {
      bf8 kb = *reinterpret_cast<const bf8*>(&ls_k[(n * 16 + lr) * 96 + h * 32 + kg * 8]);
      f32x4 z = {0.f, 0.f, 0.f, 0.f};
      f32x4 sv = __builtin_amdgcn_mfma_f32_16x16x32_bf16(qa, kb, z, 0, 0, 0);
      const int  j  = n * 16 + lr;
      const bool jx = (j >> 4) >= 2;
      const bool jy = ((j >> 2) & 3) >= 2;
      #pragma unroll
      for (int ri = 0; ri < 4; ++ri) {
        const int i = drow0 + ri;
        const bool kill = (mx && (((i >> 4) >= 2) != jx)) ||
                          (my && ((((i >> 2) & 3) >= 2) != jy));
        ls_s[i * 67 + j] = kill ? -1e30f : sv[ri];
      }
    }
    __syncthreads();
    {   // softmax: 4 threads per row
      const int row = tid >> 2, sub = tid & 3;
      float v[16];
      float m = -3e38f;
      #pragma unroll
      for (int jj = 0; jj < 16; ++jj) {
        v[jj] = ls_s[row * 67 + sub * 16 + jj];
        m = fmaxf(m, v[jj]);
      }
      m = fmaxf(m, __shfl_xor(m, 1));
      m = fmaxf(m, __shfl_xor(m, 2));
      float sum = 0.f;
      #pragma unroll
      for (int jj = 0; jj < 16; ++jj) { v[jj] = __expf(v[jj] - m); sum += v[jj]; }
      sum += __shfl_xor(sum, 1);
      sum += __shfl_xor(sum, 2);
      const float inv = 1.f / sum;
      unsigned* pw = reinterpret_cast<unsigned*>(&ls_p[row * 72 + sub * 16]);
      #pragma unroll
      for (int jj = 0; jj < 8; ++jj) pw[jj] = pk2(v[2 * jj] * inv, v[2 * jj + 1] * inv);
    }
    __syncthreads();
    #pragma unroll
    for (int t = 0; t < 2; ++t) {
      bf8 pa = *reinterpret_cast<const bf8*>(&ls_p[arow * 72 + t * 32 + kg * 8]);
      #pragma unroll
      for (int n = 0; n < 2; ++n) {
        bf8 vb = *reinterpret_cast<const bf8*>(&ls_vt[(h * 32 + n * 16 + lr) * 72 + t * 32 + kg * 8]);
        acc_o[h][n] = __builtin_amdgcn_mfma_f32_16x16x32_bf16(pa, vb, acc_o[h][n], 0, 0, 0);
      }
    }
    __syncthreads();   // protects ls_s (next S store) and ls_p (next softmax)
  }

  // ---- Phase 4: O -> LDS (reuse ls_q), out-proj, bias, rolled store ----------
  #pragma unroll
  for (int h = 0; h < 3; ++h)
    #pragma unroll
    for (int n = 0; n < 2; ++n)
      #pragma unroll
      for (int ri = 0; ri < 4; ++ri)
        lo[(drow0 + ri) * 96 + h * 32 + n * 16 + lr] = f2b(acc_o[h][n][ri]);
  __syncthreads();

  bf8 oa0 = *reinterpret_cast<const bf8*>(&lo[arow * 96 +  0 + kg * 8]);
  bf8 oa1 = *reinterpret_cast<const bf8*>(&lo[arow * 96 + 32 + kg * 8]);
  bf8 oa2 = *reinterpret_cast<const bf8*>(&lo[arow * 96 + 64 + kg * 8]);

  size_t obase[4];
  #pragma unroll
  for (int ri = 0; ri < 4; ++ri) {
    const int s  = drow0 + ri;
    const int sx = s >> 4, sy = (s >> 2) & 3, sz = s & 3;
    const int gx = (p * 4 + sx + 2) & 63;
    const int gy = (q * 4 + sy + 2) & 63;
    const int gz = (r * 4 + sz + 2) & 63;
    obase[ri] = (size_t)((gx * 64 + gy) * 64 + gz) * 96;
  }
  #pragma unroll
  for (int n = 0; n < 6; ++n) {
    f32x4 acc = {0.f, 0.f, 0.f, 0.f};
    const short* wrow = &wob[(n * 16 + lr) * 96 + kg * 8];
    acc = __builtin_amdgcn_mfma_f32_16x16x32_bf16(oa0, *reinterpret_cast<const bf8*>(wrow +  0), acc, 0, 0, 0);
    acc = __builtin_amdgcn_mfma_f32_16x16x32_bf16(oa1, *reinterpret_cast<const bf8*>(wrow + 32), acc, 0, 0, 0);
    acc = __builtin_amdgcn_mfma_f32_16x16x32_bf16(oa2, *reinterpret_cast<const bf8*>(wrow + 64), acc, 0, 0, 0);
    const float bias = bo[n * 16 + lr];
    #pragma unroll
    for (int ri = 0; ri < 4; ++ri)
      out[obase[ri] + n * 16 + lr] = acc[ri] + bias;
  }
}

extern "C" void kernel_launch(void* const* d_in, const int* in_sizes, int n_in,
                              void* d_out, int out_size, void* d_ws, size_t ws_size,
                              hipStream_t stream) {
  const float* x  = (const float*)d_in[0];
  const float* wq = (const float*)d_in[1];
  const float* wo = (const float*)d_in[2];
  const float* bo = (const float*)d_in[3];
  // d_in[4..6] = x_mask/y_mask/z_mask: computed analytically in-kernel.

  short* wqb = (short*)d_ws;             // 288*96 bf16
  short* wob = wqb + 288 * 96;           // 96*96  bf16

  prep_weights<<<(288 * 96 + 255) / 256, 256, 0, stream>>>(wq, wo, wqb, wob);
  fused_swin3d<<<4096, 256, 0, stream>>>(x, wqb, wob, bo, (float*)d_out);
}

// Round 2
// 108.753 us; speedup vs baseline: 1.1938x; 1.1938x over previous
//
#include <hip/hip_runtime.h>
#include <hip/hip_bf16.h>

// 3D shifted-window attention, fully fused: per-block = one output window.
// Output window (p,q,r): QK from window (q,r,p), V from (p,q,r),
// x_mask iff q==15, y_mask iff r==15 (z_mask never applied - faithful to ref).
// Roll(-2) folded into loads, roll(+2) folded into stores.
//
// R2: in-register softmax (no ls_s), 4 barriers total (ls_q/ls_p/lo are
// per-wave private), bank-conflict-free strides (100/68/72 shorts), b64 Vt
// stores, 51KB LDS -> 3 blocks/CU.

using bf8   = __attribute__((ext_vector_type(8))) short;   // 8 x bf16 (4 VGPR)
using f32x4 = __attribute__((ext_vector_type(4))) float;

#define SQK 100   // ls_q / ls_k / ys row stride (shorts); == 4 mod 16 -> conflict-free
#define SP   68   // ls_p row stride (shorts); == 4 mod 16
#define SVT  72   // ls_vt row stride (shorts)

__device__ __forceinline__ short f2b(float f) {
  __hip_bfloat16 h = __float2bfloat16(f);
  return *reinterpret_cast<short*>(&h);
}
__device__ __forceinline__ unsigned pk2(float a, float b) {
  return (unsigned)(unsigned short)f2b(a) | ((unsigned)(unsigned short)f2b(b) << 16);
}

__global__ void prep_weights(const float* __restrict__ wq, const float* __restrict__ wo,
                             short* __restrict__ wqb, short* __restrict__ wob) {
  int i = blockIdx.x * 256 + threadIdx.x;
  const float QS = 0.17677669529663687f;   // 1/sqrt(32), folded into W_q rows
  if (i < 288 * 96) wqb[i] = f2b(wq[i] * (i < 96 * 96 ? QS : 1.0f));
  if (i < 96 * 96)  wob[i] = f2b(wo[i]);
}

// Load one 4x4x4 window of x (rolled by -2 on each axis) into LDS bf16 [64][SQK].
__device__ __forceinline__ void load_window_bf16(short* __restrict__ ys,
    const float* __restrict__ x, int wx, int wy, int wz, int tid) {
  #pragma unroll
  for (int it = 0; it < 6; ++it) {
    int idx = tid + it * 256;            // 0..1535 float4s
    int s   = idx / 24;
    int c4  = (idx - s * 24) * 4;
    int sx = s >> 4, sy = (s >> 2) & 3, sz = s & 3;
    int gx = (wx * 4 + sx + 2) & 63;
    int gy = (wy * 4 + sy + 2) & 63;
    int gz = (wz * 4 + sz + 2) & 63;
    const float4 v = *reinterpret_cast<const float4*>(
        &x[(size_t)((gx * 64 + gy) * 64 + gz) * 96 + c4]);
    uint2 pk; pk.x = pk2(v.x, v.y); pk.y = pk2(v.z, v.w);
    *reinterpret_cast<uint2*>(&ys[s * SQK + c4]) = pk;   // 8B aligned
  }
}

__global__ __launch_bounds__(256, 3)
void fused_swin3d(const float* __restrict__ x,
                  const short* __restrict__ wqb,   // [288][96] bf16 (Q rows pre-scaled)
                  const short* __restrict__ wob,   // [96][96]  bf16
                  const float* __restrict__ bo,    // [96] fp32
                  float* __restrict__ out) {
  __shared__ short ls_q [64 * SQK];   // Q bf16 [s][ch]; per-wave private; reused as O
  __shared__ short ls_k [64 * SQK];   // K bf16 [s][ch]; shared (B-frags)
  __shared__ short ls_vt[96 * SVT];   // V bf16 transposed [ch][s]; shared
  __shared__ short ls_yp[64 * SQK];   // x-window staging; later P [i][j] stride SP (private)

  short* ys = ls_yp;
  short* lp = ls_yp;
  short* lo = ls_q;

  const int w  = blockIdx.x;
  const int p  = w >> 8, q = (w >> 4) & 15, r = w & 15;
  const int tid  = threadIdx.x;
  const int lane = tid & 63;
  const int wv   = tid >> 6;          // wave id = M-tile (rows wv*16..wv*16+15)
  const int lr   = lane & 15;
  const int kg   = lane >> 4;
  const int arow  = wv * 16 + lr;     // A/B-frag row
  const int drow0 = wv * 16 + kg * 4; // D-frag first row

  // ---- Phase 1: ys = x(window (q,r,p)); compute Q (pre-scaled) and K ---------
  load_window_bf16(ys, x, q, r, p, tid);
  __syncthreads();                                       // bar1: ys1 ready
  bf8 af0 = *reinterpret_cast<const bf8*>(&ys[arow * SQK +  0 + kg * 8]);
  bf8 af1 = *reinterpret_cast<const bf8*>(&ys[arow * SQK + 32 + kg * 8]);
  bf8 af2 = *reinterpret_cast<const bf8*>(&ys[arow * SQK + 64 + kg * 8]);
  #pragma unroll
  for (int n = 0; n < 12; ++n) {
    f32x4 acc = {0.f, 0.f, 0.f, 0.f};
    const short* wrow = &wqb[(n * 16 + lr) * 96 + kg * 8];
    acc = __builtin_amdgcn_mfma_f32_16x16x32_bf16(af0, *reinterpret_cast<const bf8*>(wrow +  0), acc, 0, 0, 0);
    acc = __builtin_amdgcn_mfma_f32_16x16x32_bf16(af1, *reinterpret_cast<const bf8*>(wrow + 32), acc, 0, 0, 0);
    acc = __builtin_amdgcn_mfma_f32_16x16x32_bf16(af2, *reinterpret_cast<const bf8*>(wrow + 64), acc, 0, 0, 0);
    short* dst = (n < 6) ? &ls_q[0] : &ls_k[0];
    const int nn = (n < 6) ? n : n - 6;
    #pragma unroll
    for (int ri = 0; ri < 4; ++ri)
      dst[(drow0 + ri) * SQK + nn * 16 + lr] = f2b(acc[ri]);
  }
  __syncthreads();                                       // bar2: K ready, ys1 reads done

  // ---- Phase 2: ys = x(window (p,q,r)); compute V, store transposed (b64) ----
  load_window_bf16(ys, x, p, q, r, tid);
  __syncthreads();                                       // bar3: ys2 ready
  af0 = *reinterpret_cast<const bf8*>(&ys[arow * SQK +  0 + kg * 8]);
  af1 = *reinterpret_cast<const bf8*>(&ys[arow * SQK + 32 + kg * 8]);
  af2 = *reinterpret_cast<const bf8*>(&ys[arow * SQK + 64 + kg * 8]);
  #pragma unroll
  for (int n = 0; n < 6; ++n) {
    f32x4 acc = {0.f, 0.f, 0.f, 0.f};
    const short* wrow = &wqb[(192 + n * 16 + lr) * 96 + kg * 8];
    acc = __builtin_amdgcn_mfma_f32_16x16x32_bf16(af0, *reinterpret_cast<const bf8*>(wrow +  0), acc, 0, 0, 0);
    acc = __builtin_amdgcn_mfma_f32_16x16x32_bf16(af1, *reinterpret_cast<const bf8*>(wrow + 32), acc, 0, 0, 0);
    acc = __builtin_amdgcn_mfma_f32_16x16x32_bf16(af2, *reinterpret_cast<const bf8*>(wrow + 64), acc, 0, 0, 0);
    // Vt[ch = n*16+lr][s = drow0..drow0+3]: 4 consecutive shorts -> one b64 store
    short4 vpk;
    vpk.x = f2b(acc[0]); vpk.y = f2b(acc[1]); vpk.z = f2b(acc[2]); vpk.w = f2b(acc[3]);
    *reinterpret_cast<short4*>(&ls_vt[(n * 16 + lr) * SVT + drow0]) = vpk;
  }
  __syncthreads();                                       // bar4: Vt ready, ys2 reads done
  // -------- no further barriers: ls_q/lp/lo are per-wave private --------------

  // ---- Phase 3: per-head S = QK^T (+mask), in-register softmax, O += P V -----
  const bool mx = (q == 15), my = (r == 15);
  // mask predicates collapse: jx=(n>=2), jy=(lr>=8), ix=(wv>=2), iy=(kg>=2)
  const bool ky = my && ((kg >= 2) != (lr >= 8));
  f32x4 acc_o[3][2];
  #pragma unroll
  for (int h = 0; h < 3; ++h)
    #pragma unroll
    for (int n = 0; n < 2; ++n)
      acc_o[h][n] = (f32x4){0.f, 0.f, 0.f, 0.f};

  #pragma unroll
  for (int h = 0; h < 3; ++h) {
    bf8 qa = *reinterpret_cast<const bf8*>(&ls_q[arow * SQK + h * 32 + kg * 8]);
    f32x4 sv[4];
    #pragma unroll
    for (int n = 0; n < 4; ++n) {
      bf8 kb = *reinterpret_cast<const bf8*>(&ls_k[(n * 16 + lr) * SQK + h * 32 + kg * 8]);
      f32x4 z = {0.f, 0.f, 0.f, 0.f};
      sv[n] = __builtin_amdgcn_mfma_f32_16x16x32_bf16(qa, kb, z, 0, 0, 0);
      const bool kill = ky || (mx && ((wv >= 2) != (n >= 2)));
      if (kill) sv[n] = (f32x4){-1e30f, -1e30f, -1e30f, -1e30f};
    }
    // in-register softmax: row i = drow0+ri lives in the 16 lanes sharing kg
    #pragma unroll
    for (int ri = 0; ri < 4; ++ri) {
      float s0 = sv[0][ri], s1 = sv[1][ri], s2 = sv[2][ri], s3 = sv[3][ri];
      float m = fmaxf(fmaxf(s0, s1), fmaxf(s2, s3));
      m = fmaxf(m, __shfl_xor(m, 1));
      m = fmaxf(m, __shfl_xor(m, 2));
      m = fmaxf(m, __shfl_xor(m, 4));
      m = fmaxf(m, __shfl_xor(m, 8));
      float e0 = __expf(s0 - m), e1 = __expf(s1 - m);
      float e2 = __expf(s2 - m), e3 = __expf(s3 - m);
      float sum = (e0 + e1) + (e2 + e3);
      sum += __shfl_xor(sum, 1);
      sum += __shfl_xor(sum, 2);
      sum += __shfl_xor(sum, 4);
      sum += __shfl_xor(sum, 8);
      const float inv = 1.f / sum;
      const int prow = (drow0 + ri) * SP;
      lp[prow +  0 + lr] = f2b(e0 * inv);
      lp[prow + 16 + lr] = f2b(e1 * inv);
      lp[prow + 32 + lr] = f2b(e2 * inv);
      lp[prow + 48 + lr] = f2b(e3 * inv);
    }
    // P V (same-wave LDS ordering: no barrier needed)
    #pragma unroll
    for (int t = 0; t < 2; ++t) {
      bf8 pa = *reinterpret_cast<const bf8*>(&lp[arow * SP + t * 32 + kg * 8]);
      #pragma unroll
      for (int n = 0; n < 2; ++n) {
        bf8 vb = *reinterpret_cast<const bf8*>(&ls_vt[(h * 32 + n * 16 + lr) * SVT + t * 32 + kg * 8]);
        acc_o[h][n] = __builtin_amdgcn_mfma_f32_16x16x32_bf16(pa, vb, acc_o[h][n], 0, 0, 0);
      }
    }
  }

  // ---- Phase 4: O -> LDS (reuse ls_q; wave-private), out-proj, bias, store ---
  #pragma unroll
  for (int h = 0; h < 3; ++h)
    #pragma unroll
    for (int n = 0; n < 2; ++n)
      #pragma unroll
      for (int ri = 0; ri < 4; ++ri)
        lo[(drow0 + ri) * SQK + h * 32 + n * 16 + lr] = f2b(acc_o[h][n][ri]);

  bf8 oa0 = *reinterpret_cast<const bf8*>(&lo[arow * SQK +  0 + kg * 8]);
  bf8 oa1 = *reinterpret_cast<const bf8*>(&lo[arow * SQK + 32 + kg * 8]);
  bf8 oa2 = *reinterpret_cast<const bf8*>(&lo[arow * SQK + 64 + kg * 8]);

  float bias[6];
  #pragma unroll
  for (int n = 0; n < 6; ++n) bias[n] = bo[n * 16 + lr];

  size_t obase[4];
  #pragma unroll
  for (int ri = 0; ri < 4; ++ri) {
    const int s  = drow0 + ri;
    const int sx = s >> 4, sy = (s >> 2) & 3, sz = s & 3;
    const int gx = (p * 4 + sx + 2) & 63;
    const int gy = (q * 4 + sy + 2) & 63;
    const int gz = (r * 4 + sz + 2) & 63;
    obase[ri] = (size_t)((gx * 64 + gy) * 64 + gz) * 96;
  }
  #pragma unroll
  for (int n = 0; n < 6; ++n) {
    f32x4 acc = {0.f, 0.f, 0.f, 0.f};
    const short* wrow = &wob[(n * 16 + lr) * 96 + kg * 8];
    acc = __builtin_amdgcn_mfma_f32_16x16x32_bf16(oa0, *reinterpret_cast<const bf8*>(wrow +  0), acc, 0, 0, 0);
    acc = __builtin_amdgcn_mfma_f32_16x16x32_bf16(oa1, *reinterpret_cast<const bf8*>(wrow + 32), acc, 0, 0, 0);
    acc = __builtin_amdgcn_mfma_f32_16x16x32_bf16(oa2, *reinterpret_cast<const bf8*>(wrow + 64), acc, 0, 0, 0);
    #pragma unroll
    for (int ri = 0; ri < 4; ++ri)
      out[obase[ri] + n * 16 + lr] = acc[ri] + bias[n];
  }
}

extern "C" void kernel_launch(void* const* d_in, const int* in_sizes, int n_in,
                              void* d_out, int out_size, void* d_ws, size_t ws_size,
                              hipStream_t stream) {
  const float* x  = (const float*)d_in[0];
  const float* wq = (const float*)d_in[1];
  const float* wo = (const float*)d_in[2];
  const float* bo = (const float*)d_in[3];
  // d_in[4..6] = x_mask/y_mask/z_mask: applied analytically in-kernel.

  short* wqb = (short*)d_ws;             // 288*96 bf16
  short* wob = wqb + 288 * 96;           // 96*96  bf16

  prep_weights<<<(288 * 96 + 255) / 256, 256, 0, stream>>>(wq, wo, wqb, wob);
  fused_swin3d<<<4096, 256, 0, stream>>>(x, wqb, wob, bo, (float*)d_out);
}